// Round 14
// baseline (193.367 us; speedup 1.0000x reference)
//
#include <hip/hip_runtime.h>
#include <hip/hip_fp16.h>
#include <math.h>

#define N_NODES 50000
#define N_EDGES 800000
#define NGRAPH  512
#define BN_EPS  1e-5f
#define SCAN_BLOCKS 196   // ceil(50000/256)
#define NREP 32           // stats replication for k_gather2
#define NREP3 16          // stats replication for k_poolfc1

// ------- degree count + rank; fused graph-boundary scan -------
__global__ void k_degb(const int* __restrict__ dst, int* __restrict__ cnt,
                       int* __restrict__ rank, const int* __restrict__ batch,
                       int* __restrict__ gstart) {
    int e = blockIdx.x * blockDim.x + threadIdx.x;
    if (e < N_EDGES) rank[e] = atomicAdd(&cnt[dst[e]], 1);
    if (e < N_NODES) {
        int b = batch[e];
        int prev = (e == 0) ? -1 : batch[e - 1];
        for (int g = prev + 1; g <= b; g++) gstart[g] = e;
        if (e == N_NODES - 1)
            for (int g = b + 1; g <= NGRAPH; g++) gstart[g] = N_NODES;
    }
}

// ------- scan A: per-256-chunk exclusive scan (coalesced) + dinv fused ------
__global__ __launch_bounds__(256) void k_scanA(const int* __restrict__ cnt,
        float* __restrict__ dinv, int* __restrict__ local, int* __restrict__ bsum) {
    int t = threadIdx.x;
    int n = blockIdx.x * 256 + t;
    int v = 0;
    if (n < N_NODES) {
        v = cnt[n];
        dinv[n] = rsqrtf((float)v + 1.0f);
    }
    __shared__ int sh[256];
    sh[t] = v;
    __syncthreads();
    for (int off = 1; off < 256; off <<= 1) {
        int u = (t >= off) ? sh[t - off] : 0;
        __syncthreads();
        sh[t] += u;
        __syncthreads();
    }
    if (n < N_NODES) local[n] = sh[t] - v;
    if (t == 255) bsum[blockIdx.x] = sh[255];
}

// ------- scan BC fused ------
__global__ __launch_bounds__(256) void k_scanBC(const int* __restrict__ bsum,
        const int* __restrict__ local, int* __restrict__ row_start) {
    __shared__ int sh[256];
    __shared__ int boff;
    int t = threadIdx.x;
    int v = (t < SCAN_BLOCKS) ? bsum[t] : 0;
    sh[t] = v;
    __syncthreads();
    for (int off = 1; off < 256; off <<= 1) {
        int u = (t >= off) ? sh[t - off] : 0;
        __syncthreads();
        sh[t] += u;
        __syncthreads();
    }
    if (t == blockIdx.x) boff = sh[t] - v;
    __syncthreads();
    int n = blockIdx.x * 256 + t;
    if (n < N_NODES) row_start[n] = local[n] + boff;
}

// ------- CSR fill (no atomics): pos = row_start[dst] + rank[e] -------
__global__ void k_fill(const int* __restrict__ src, const int* __restrict__ dst,
                       const int* __restrict__ row_start, const int* __restrict__ rank,
                       const float* __restrict__ dinv, unsigned* __restrict__ entries) {
    int e = blockIdx.x * blockDim.x + threadIdx.x;
    if (e >= N_EDGES) return;
    int s = src[e], t = dst[e];
    int pos = row_start[t] + rank[e];
    float co = dinv[s] * dinv[t];
    unsigned cb = (unsigned)__half_as_ushort(__float2half(co));
    entries[pos] = (cb << 16) | (unsigned)s;
}

// ------- layer-1 gather: 4 threads/node, 4-deep pipeline + fused BN1 stats --
__global__ __launch_bounds__(256) void k_gather1(const int* __restrict__ row_start,
        const int* __restrict__ cnt, const unsigned* __restrict__ entries,
        const float* __restrict__ dinv, const float4* __restrict__ x,
        float4* __restrict__ aggx, const float* __restrict__ W1,
        const float* __restrict__ b1, float* __restrict__ s1, float* __restrict__ q1) {
    __shared__ float axs[64][4];
    __shared__ float w1s[4][128];
    __shared__ float b1s[128];
    __shared__ float red1[256], red2[256];
    int tid = threadIdx.x;
    if (tid < 128) {
        b1s[tid] = b1[tid];
        for (int c2 = 0; c2 < 4; c2++) w1s[c2][tid] = W1[c2 * 128 + tid];
    }
    int t = blockIdx.x * 256 + tid;
    int n = t >> 2, p = t & 3;
    int slot = tid >> 2;
    if (n < N_NODES) {
        int rs = row_start[n], cn = cnt[n];
        const unsigned* ep = entries + rs;
        float4 accA = make_float4(0.f, 0.f, 0.f, 0.f);
        float4 accB = make_float4(0.f, 0.f, 0.f, 0.f);
        int i = p;
        for (; i + 12 < cn; i += 16) {
            unsigned e0 = ep[i], e1 = ep[i + 4], e2 = ep[i + 8], e3 = ep[i + 12];
            float4 v0 = x[e0 & 0xFFFFu];
            float4 v1 = x[e1 & 0xFFFFu];
            float4 v2 = x[e2 & 0xFFFFu];
            float4 v3 = x[e3 & 0xFFFFu];
            float c0 = __half2float(__ushort_as_half((unsigned short)(e0 >> 16)));
            float c1 = __half2float(__ushort_as_half((unsigned short)(e1 >> 16)));
            float c2 = __half2float(__ushort_as_half((unsigned short)(e2 >> 16)));
            float c3 = __half2float(__ushort_as_half((unsigned short)(e3 >> 16)));
            accA.x = fmaf(v0.x, c0, accA.x); accA.y = fmaf(v0.y, c0, accA.y);
            accA.z = fmaf(v0.z, c0, accA.z); accA.w = fmaf(v0.w, c0, accA.w);
            accB.x = fmaf(v1.x, c1, accB.x); accB.y = fmaf(v1.y, c1, accB.y);
            accB.z = fmaf(v1.z, c1, accB.z); accB.w = fmaf(v1.w, c1, accB.w);
            accA.x = fmaf(v2.x, c2, accA.x); accA.y = fmaf(v2.y, c2, accA.y);
            accA.z = fmaf(v2.z, c2, accA.z); accA.w = fmaf(v2.w, c2, accA.w);
            accB.x = fmaf(v3.x, c3, accB.x); accB.y = fmaf(v3.y, c3, accB.y);
            accB.z = fmaf(v3.z, c3, accB.z); accB.w = fmaf(v3.w, c3, accB.w);
        }
        for (; i < cn; i += 4) {
            unsigned e = ep[i];
            float co = __half2float(__ushort_as_half((unsigned short)(e >> 16)));
            float4 v = x[e & 0xFFFFu];
            accA.x = fmaf(v.x, co, accA.x); accA.y = fmaf(v.y, co, accA.y);
            accA.z = fmaf(v.z, co, accA.z); accA.w = fmaf(v.w, co, accA.w);
        }
        float ax = accA.x + accB.x, ay = accA.y + accB.y;
        float az = accA.z + accB.z, aw = accA.w + accB.w;
        ax += __shfl_xor(ax, 1); ax += __shfl_xor(ax, 2);
        ay += __shfl_xor(ay, 1); ay += __shfl_xor(ay, 2);
        az += __shfl_xor(az, 1); az += __shfl_xor(az, 2);
        aw += __shfl_xor(aw, 1); aw += __shfl_xor(aw, 2);
        if (p == 0) {
            float di = dinv[n], c = di * di;
            float4 a = x[n];
            float4 r = make_float4(fmaf(a.x, c, ax), fmaf(a.y, c, ay),
                                   fmaf(a.z, c, az), fmaf(a.w, c, aw));
            aggx[n] = r;
            axs[slot][0] = r.x; axs[slot][1] = r.y;
            axs[slot][2] = r.z; axs[slot][3] = r.w;
        }
    }
    __syncthreads();
    // phase 2: BN1 stats over this block's 64 nodes, channel-parallel
    int ch = tid & 127, half = tid >> 7;   // half in {0,1} -> slots 0-31 / 32-63
    int gbase = blockIdx.x * 64;
    float ps = 0.f, pq = 0.f;
    for (int si = 0; si < 32; si++) {
        int sl = half * 32 + si;
        if (gbase + sl < N_NODES) {
            float h = fmaf(axs[sl][0], w1s[0][ch], fmaf(axs[sl][1], w1s[1][ch],
                      fmaf(axs[sl][2], w1s[2][ch], fmaf(axs[sl][3], w1s[3][ch], b1s[ch]))));
            h = fmaxf(h, 0.f);
            ps += h; pq += h * h;
        }
    }
    red1[tid] = ps;
    red2[tid] = pq;
    __syncthreads();
    if (tid < 128) {
        atomicAdd(&s1[tid], red1[tid] + red1[tid + 128]);
        atomicAdd(&q1[tid], red2[tid] + red2[tid + 128]);
    }
}

// ------- fold BN1 into W2 -> W2f (fp16), d2 (fp32) ----------------
__global__ __launch_bounds__(128) void k_fold1(const float* __restrict__ s1,
        const float* __restrict__ q1, const float* __restrict__ g1,
        const float* __restrict__ be1, const float* __restrict__ W2,
        __half* __restrict__ W2f, float* __restrict__ d2) {
    __shared__ float a[128], c[128];
    int t = threadIdx.x;
    {
        float mean = s1[t] / (float)N_NODES;
        float var  = q1[t] / (float)N_NODES - mean * mean;
        float aa   = rsqrtf(var + BN_EPS) * g1[t];
        a[t] = aa;
        c[t] = be1[t] - mean * aa;
    }
    __syncthreads();
    if (t < 64) {
        float dd = 0.f;
        for (int k = 0; k < 128; k++) {
            float wv = W2[k * 64 + t];
            W2f[k * 64 + t] = __float2half(a[k] * wv);
            dd = fmaf(c[k], wv, dd);
        }
        d2[t] = dd;
    }
}

// ------- fused: recompute h1 tile from aggx, GEMM vs fp16 W2f -> h2 (fp16) --
__global__ __launch_bounds__(256) void k_h2(const float4* __restrict__ aggx,
        const float* __restrict__ W1, const float* __restrict__ b1,
        const __half* __restrict__ W2f, const float* __restrict__ d2,
        __half* __restrict__ h2) {
    __shared__ __half w[128 * 64];
    __shared__ float hs[32][128];
    __shared__ float w1s[4][128];
    __shared__ float b1s[128];
    int tid = threadIdx.x;
    for (int i = tid; i < 1024; i += 256)
        ((uint4*)w)[i] = ((const uint4*)W2f)[i];
    if (tid < 128) {
        b1s[tid] = b1[tid];
        for (int c = 0; c < 4; c++) w1s[c][tid] = W1[c * 128 + tid];
    }
    __syncthreads();
    int n0 = blockIdx.x * 32;
    for (int i = tid; i < 4096; i += 256) {
        int nn = n0 + (i >> 7), j = i & 127;
        float4 a = aggx[min(nn, N_NODES - 1)];
        float h = fmaf(a.x, w1s[0][j], fmaf(a.y, w1s[1][j],
                  fmaf(a.z, w1s[2][j], fmaf(a.w, w1s[3][j], b1s[j]))));
        hs[i >> 7][j] = fmaxf(h, 0.f);
    }
    __syncthreads();
    int j = tid & 63, q = tid >> 6;
    float acc[8];
#pragma unroll
    for (int t = 0; t < 8; t++) acc[t] = 0.f;
    for (int k = 0; k < 128; k++) {
        float wv = __half2float(w[k * 64 + j]);
#pragma unroll
        for (int t = 0; t < 8; t++)
            acc[t] = fmaf(hs[q * 8 + t][k], wv, acc[t]);
    }
    float dj = d2[j];
#pragma unroll
    for (int t = 0; t < 8; t++) {
        int n = n0 + q * 8 + t;
        if (n < N_NODES) h2[n * 64 + j] = __float2half(acc[t] + dj);
    }
}

// ---- helper: 8 halfs (uint4) * coef -> acc[8] ----
__device__ __forceinline__ void fma8(uint4 v, float c, float* acc) {
    float2 f0 = __half22float2(*reinterpret_cast<const __half2*>(&v.x));
    float2 f1 = __half22float2(*reinterpret_cast<const __half2*>(&v.y));
    float2 f2 = __half22float2(*reinterpret_cast<const __half2*>(&v.z));
    float2 f3 = __half22float2(*reinterpret_cast<const __half2*>(&v.w));
    acc[0] = fmaf(f0.x, c, acc[0]); acc[1] = fmaf(f0.y, c, acc[1]);
    acc[2] = fmaf(f1.x, c, acc[2]); acc[3] = fmaf(f1.y, c, acc[3]);
    acc[4] = fmaf(f2.x, c, acc[4]); acc[5] = fmaf(f2.y, c, acc[5]);
    acc[6] = fmaf(f3.x, c, acc[6]); acc[7] = fmaf(f3.y, c, acc[7]);
}

// ------- layer-2 gather v12 (unchanged): grid-stride, 2 nodes/wave ----------
__global__ __launch_bounds__(256) void k_gather2(const int* __restrict__ row_start,
        const int* __restrict__ cnt, const unsigned* __restrict__ entries,
        const float* __restrict__ dinv, const uint4* __restrict__ h2q,
        const float* __restrict__ b2, uint4* __restrict__ out2q,
        float* __restrict__ s2rep, float* __restrict__ q2rep) {
    int lane = threadIdx.x & 63;
    int l32 = lane & 31;
    int es = l32 >> 3;
    int j = l32 & 7;
    int wid = blockIdx.x * 4 + (threadIdx.x >> 6);
    int nwaves = gridDim.x * 4;

    float4 blo = ((const float4*)b2)[2 * j], bhi = ((const float4*)b2)[2 * j + 1];
    float bb[8] = {blo.x, blo.y, blo.z, blo.w, bhi.x, bhi.y, bhi.z, bhi.w};
    float ps[8], pq[8];
#pragma unroll
    for (int t = 0; t < 8; t++) { ps[t] = 0.f; pq[t] = 0.f; }

    for (int base = wid * 2; base < N_NODES; base += nwaves * 2) {
        int n = base + (lane >> 5);
        int rs = row_start[n];
        int cn = cnt[n];
        float di = dinv[n];
        float sc = di * di;
        int cm = max(cn, __shfl(cn, lane ^ 32));

        float accA[8], accB[8];
#pragma unroll
        for (int t = 0; t < 8; t++) { accA[t] = 0.f; accB[t] = 0.f; }

        const unsigned* ep = entries + rs;
        for (int i = 0; i < cm; i += 32) {
            int rem = cn - i;
            unsigned eld = (l32 < rem) ? ep[i + l32] : 0u;
            int nk = (min(32, cm - i) + 7) >> 3;
            uint4 va[4], vb[4];
            float ca[4], cb[4];
#pragma unroll
            for (int k = 0; k < 4; k++) {
                if (k < nk) {
                    unsigned ea = (unsigned)__shfl((int)eld, 8 * k + es, 32);
                    unsigned eb = (unsigned)__shfl((int)eld, 8 * k + 4 + es, 32);
                    ca[k] = __half2float(__ushort_as_half((unsigned short)(ea >> 16)));
                    cb[k] = __half2float(__ushort_as_half((unsigned short)(eb >> 16)));
                    va[k] = h2q[(ea & 0xFFFFu) * 8 + j];
                    vb[k] = h2q[(eb & 0xFFFFu) * 8 + j];
                }
            }
#pragma unroll
            for (int k = 0; k < 4; k++) {
                if (k < nk) {
                    fma8(va[k], ca[k], accA);
                    fma8(vb[k], cb[k], accB);
                }
            }
        }
#pragma unroll
        for (int t = 0; t < 8; t++) {
            float a = accA[t] + accB[t];
            a += __shfl_xor(a, 8);
            a += __shfl_xor(a, 16);
            accA[t] = a;
        }
        if (es == 0) {
            uint4 sv = h2q[n * 8 + j];
            float2 f0 = __half22float2(*reinterpret_cast<const __half2*>(&sv.x));
            float2 f1 = __half22float2(*reinterpret_cast<const __half2*>(&sv.y));
            float2 f2 = __half22float2(*reinterpret_cast<const __half2*>(&sv.z));
            float2 f3 = __half22float2(*reinterpret_cast<const __half2*>(&sv.w));
            float s8[8] = {f0.x, f0.y, f1.x, f1.y, f2.x, f2.y, f3.x, f3.y};
            float r[8];
#pragma unroll
            for (int t = 0; t < 8; t++) {
                r[t] = fmaxf(fmaf(s8[t], sc, accA[t]) + bb[t], 0.f);
                ps[t] += r[t];
                pq[t] += r[t] * r[t];
            }
            uint4 o;
            __half2 hp;
            hp = __floats2half2_rn(r[0], r[1]); o.x = *reinterpret_cast<unsigned*>(&hp);
            hp = __floats2half2_rn(r[2], r[3]); o.y = *reinterpret_cast<unsigned*>(&hp);
            hp = __floats2half2_rn(r[4], r[5]); o.z = *reinterpret_cast<unsigned*>(&hp);
            hp = __floats2half2_rn(r[6], r[7]); o.w = *reinterpret_cast<unsigned*>(&hp);
            out2q[n * 8 + j] = o;
        }
    }
    __shared__ float ssum[64], sq[64];
    if (threadIdx.x < 64) { ssum[threadIdx.x] = 0.f; sq[threadIdx.x] = 0.f; }
    __syncthreads();
    if (es == 0) {
#pragma unroll
        for (int t = 0; t < 8; t++) {
            atomicAdd(&ssum[8 * j + t], ps[t]);
            atomicAdd(&sq[8 * j + t], pq[t]);
        }
    }
    __syncthreads();
    if (threadIdx.x < 64) {
        int rep = (blockIdx.x & (NREP - 1)) * 64;
        atomicAdd(&s2rep[rep + threadIdx.x], ssum[threadIdx.x]);
        atomicAdd(&q2rep[rep + threadIdx.x], sq[threadIdx.x]);
    }
}

// ---- 2 waves per graph: BN2-affine pool (linearity-hoisted) + fc1 + stats --
__global__ __launch_bounds__(128) void k_poolfc1(const __half* __restrict__ out2,
        const int* __restrict__ gstart, const float* __restrict__ s2rep,
        const float* __restrict__ q2rep, const float* __restrict__ g2,
        const float* __restrict__ be2, const float* __restrict__ fW1,
        const float* __restrict__ fb1, float* __restrict__ t1,
        float* __restrict__ s3rep, float* __restrict__ q3rep) {
    int g = blockIdx.x;
    int j = threadIdx.x & 63;
    int w = threadIdx.x >> 6;       // wave 0 / 1
    int s = gstart[g], e = gstart[g + 1];
    float acc = 0.f;
    int n = s + w;
    for (; n + 6 < e; n += 8) {
        float v0 = __half2float(out2[(n + 0) * 64 + j]);
        float v1 = __half2float(out2[(n + 2) * 64 + j]);
        float v2 = __half2float(out2[(n + 4) * 64 + j]);
        float v3 = __half2float(out2[(n + 6) * 64 + j]);
        acc += (v0 + v1) + (v2 + v3);
    }
    for (; n < e; n += 2) acc += __half2float(out2[n * 64 + j]);
    __shared__ float part[2][64];
    __shared__ float hgs[64];
    part[w][j] = acc;
    __syncthreads();
    if (threadIdx.x < 64) {
        float ssum = 0.f, sq = 0.f;
#pragma unroll
        for (int r = 0; r < NREP; r++) {
            ssum += s2rep[r * 64 + j];
            sq   += q2rep[r * 64 + j];
        }
        float mean = ssum / (float)N_NODES;
        float var  = sq / (float)N_NODES - mean * mean;
        float a = rsqrtf(var + BN_EPS) * g2[j];
        float c = be2[j] - mean * a;
        float asum = part[0][j] + part[1][j];
        hgs[j] = fmaf(a, asum, (float)(e - s) * c);
    }
    __syncthreads();
    if (threadIdx.x < 64) {
        float accf = fb1[j];
        for (int k = 0; k < 64; k++) accf = fmaf(hgs[k], fW1[k * 64 + j], accf);
        accf = fmaxf(accf, 0.f);
        t1[g * 64 + j] = accf;
        int rep = (g & (NREP3 - 1)) * 64;
        atomicAdd(&s3rep[rep + j], accf);
        atomicAdd(&q3rep[rep + j], accf * accf);
    }
}

// ------- bn3 (stats from 16 replicas) -> fc2+relu -> fc3 -> log_softmax ---
__global__ __launch_bounds__(256) void k_final(const float* __restrict__ t1,
        const float* __restrict__ s3rep, const float* __restrict__ q3rep,
        const float* __restrict__ g3, const float* __restrict__ be3,
        const float* __restrict__ fW2, const float* __restrict__ fb2,
        const float* __restrict__ fW3, const float* __restrict__ fb3,
        float* __restrict__ out) {
    __shared__ float w2[64 * 64];
    __shared__ float w3s[192];
    __shared__ float a3[64], c3[64], b3s[3];
    int tid = threadIdx.x;
    for (int i = tid; i < 4096; i += 256) w2[i] = fW2[i];
    if (tid < 192) w3s[tid] = fW3[tid];
    if (tid < 64) {
        float ss = 0.f, qq = 0.f;
#pragma unroll
        for (int r = 0; r < NREP3; r++) {
            ss += s3rep[r * 64 + tid];
            qq += q3rep[r * 64 + tid];
        }
        float mean = ss / (float)NGRAPH;
        float var  = qq / (float)NGRAPH - mean * mean;
        float a = rsqrtf(var + BN_EPS) * g3[tid];
        a3[tid] = a;
        c3[tid] = be3[tid] - mean * a;
    }
    if (tid < 3)  b3s[tid] = fb3[tid];
    __syncthreads();
    int lane = tid & 63, wv = tid >> 6;
    float fbj = fb2[lane];
    for (int r = blockIdx.x * 4 + wv; r < NGRAPH; r += gridDim.x * 4) {
        float acc = fbj;
        for (int k = 0; k < 64; k++) {
            float xk = fmaf(t1[r * 64 + k], a3[k], c3[k]);
            acc = fmaf(xk, w2[k * 64 + lane], acc);
        }
        acc = fmaxf(acc, 0.f);
        float o0 = acc * w3s[lane * 3 + 0];
        float o1 = acc * w3s[lane * 3 + 1];
        float o2 = acc * w3s[lane * 3 + 2];
        for (int off = 32; off; off >>= 1) {
            o0 += __shfl_down(o0, off);
            o1 += __shfl_down(o1, off);
            o2 += __shfl_down(o2, off);
        }
        if (lane == 0) {
            o0 += b3s[0]; o1 += b3s[1]; o2 += b3s[2];
            float m = fmaxf(o0, fmaxf(o1, o2));
            float lse = m + logf(expf(o0 - m) + expf(o1 - m) + expf(o2 - m));
            out[r * 3 + 0] = o0 - lse;
            out[r * 3 + 1] = o1 - lse;
            out[r * 3 + 2] = o2 - lse;
        }
    }
}

extern "C" void kernel_launch(void* const* d_in, const int* in_sizes, int n_in,
                              void* d_out, int out_size, void* d_ws, size_t ws_size,
                              hipStream_t stream) {
    const float* x   = (const float*)d_in[0];
    const int*   ei  = (const int*)d_in[1];
    const int*   bat = (const int*)d_in[2];
    const float* W1  = (const float*)d_in[3];
    const float* b1  = (const float*)d_in[4];
    const float* g1  = (const float*)d_in[5];
    const float* be1 = (const float*)d_in[6];
    const float* W2  = (const float*)d_in[7];
    const float* b2  = (const float*)d_in[8];
    const float* g2  = (const float*)d_in[9];
    const float* be2 = (const float*)d_in[10];
    const float* fW1 = (const float*)d_in[11];
    const float* fb1 = (const float*)d_in[12];
    const float* g3  = (const float*)d_in[13];
    const float* be3 = (const float*)d_in[14];
    const float* fW2 = (const float*)d_in[15];
    const float* fb2 = (const float*)d_in[16];
    const float* fW3 = (const float*)d_in[17];
    const float* fb3 = (const float*)d_in[18];

    // ---- workspace layout ----
    // zeroed region: cnt | s1 q1 | s2rep q2rep | s3rep q3rep
    int*   cnt    = (int*)d_ws;                       // N
    float* s1     = (float*)(cnt + N_NODES);          // 128
    float* q1     = s1 + 128;                         // 128
    float* s2rep  = q1 + 128;                         // NREP*64
    float* q2rep  = s2rep + NREP * 64;                // NREP*64
    float* s3rep  = q2rep + NREP * 64;                // NREP3*64
    float* q3rep  = s3rep + NREP3 * 64;               // NREP3*64
    size_t zero_floats = (size_t)N_NODES + 256 + NREP * 128 + NREP3 * 128;
    // non-zeroed scratch
    float* dinv   = q3rep + NREP3 * 64;               // N
    int*   row_start = (int*)(dinv + N_NODES);        // N
    int*   slocal = row_start + N_NODES;              // N   (scan locals)
    int*   sbsum  = slocal + N_NODES;                 // SCAN_BLOCKS (pad 256)
    int*   rank   = sbsum + 256;                      // E
    int*   gstart = rank + N_EDGES;                   // 513 (pad 520)
    unsigned* entries = (unsigned*)(gstart + 520);    // E (4B each)
    float* aggx   = (float*)(entries + N_EDGES);      // N*4 (16B aligned)
    __half* h2    = (__half*)(aggx + (size_t)N_NODES * 4);   // [N][64] halfs
    __half* out2  = h2 + (size_t)N_NODES * 64;        // [N][64] halfs
    __half* W2f   = out2 + (size_t)N_NODES * 64;      // 128*64 halfs
    float* d2     = (float*)(W2f + 128 * 64);         // 64
    float* t1     = d2 + 64;                          // 512*64

    hipMemsetAsync(d_ws, 0, zero_floats * 4, stream);

    const int* src = ei;
    const int* dst = ei + N_EDGES;

    k_degb   <<<(N_EDGES + 255) / 256, 256, 0, stream>>>(dst, cnt, rank, bat, gstart);
    k_scanA  <<<SCAN_BLOCKS, 256, 0, stream>>>(cnt, dinv, slocal, sbsum);
    k_scanBC <<<SCAN_BLOCKS, 256, 0, stream>>>(sbsum, slocal, row_start);
    k_fill   <<<(N_EDGES + 255) / 256, 256, 0, stream>>>(src, dst, row_start, rank, dinv, entries);
    k_gather1<<<(4 * N_NODES + 255) / 256, 256, 0, stream>>>(row_start, cnt, entries, dinv,
                                                             (const float4*)x, (float4*)aggx,
                                                             W1, b1, s1, q1);
    k_fold1  <<<1, 128, 0, stream>>>(s1, q1, g1, be1, W2, W2f, d2);
    k_h2     <<<(N_NODES + 31) / 32, 256, 0, stream>>>((const float4*)aggx, W1, b1, W2f, d2, h2);
    k_gather2<<<4096, 256, 0, stream>>>(row_start, cnt, entries, dinv, (const uint4*)h2, b2, (uint4*)out2, s2rep, q2rep);
    k_poolfc1<<<NGRAPH, 128, 0, stream>>>(out2, gstart, s2rep, q2rep, g2, be2, fW1, fb1, t1, s3rep, q3rep);
    k_final  <<<128, 256, 0, stream>>>(t1, s3rep, q3rep, g3, be3, fW2, fb2, fW3, fb3, (float*)d_out);
}

// Round 15
// 185.685 us; speedup vs baseline: 1.0414x; 1.0414x over previous
//
#include <hip/hip_runtime.h>
#include <hip/hip_fp16.h>
#include <math.h>

#define N_NODES 50000
#define N_EDGES 800000
#define NGRAPH  512
#define BN_EPS  1e-5f
#define SCAN_BLOCKS 196   // ceil(50000/256)
#define NREP 32           // stats replication for k_gather2
#define NREP3 16          // stats replication for k_poolfc1

// ------- degree count + rank; fused graph-boundary scan -------
__global__ void k_degb(const int* __restrict__ dst, int* __restrict__ cnt,
                       int* __restrict__ rank, const int* __restrict__ batch,
                       int* __restrict__ gstart) {
    int e = blockIdx.x * blockDim.x + threadIdx.x;
    if (e < N_EDGES) rank[e] = atomicAdd(&cnt[dst[e]], 1);
    if (e < N_NODES) {
        int b = batch[e];
        int prev = (e == 0) ? -1 : batch[e - 1];
        for (int g = prev + 1; g <= b; g++) gstart[g] = e;
        if (e == N_NODES - 1)
            for (int g = b + 1; g <= NGRAPH; g++) gstart[g] = N_NODES;
    }
}

// ------- scan A: per-256-chunk exclusive scan + dinv + x' = dinv*x ------
__global__ __launch_bounds__(256) void k_scanA(const int* __restrict__ cnt,
        float* __restrict__ dinv, const float4* __restrict__ x, float4* __restrict__ xp,
        int* __restrict__ local, int* __restrict__ bsum) {
    int t = threadIdx.x;
    int n = blockIdx.x * 256 + t;
    int v = 0;
    if (n < N_NODES) {
        v = cnt[n];
        float di = rsqrtf((float)v + 1.0f);
        dinv[n] = di;
        float4 a = x[n];
        xp[n] = make_float4(a.x * di, a.y * di, a.z * di, a.w * di);
    }
    __shared__ int sh[256];
    sh[t] = v;
    __syncthreads();
    for (int off = 1; off < 256; off <<= 1) {
        int u = (t >= off) ? sh[t - off] : 0;
        __syncthreads();
        sh[t] += u;
        __syncthreads();
    }
    if (n < N_NODES) local[n] = sh[t] - v;
    if (t == 255) bsum[blockIdx.x] = sh[255];
}

// ------- scan BC fused ------
__global__ __launch_bounds__(256) void k_scanBC(const int* __restrict__ bsum,
        const int* __restrict__ local, int* __restrict__ row_start) {
    __shared__ int sh[256];
    __shared__ int boff;
    int t = threadIdx.x;
    int v = (t < SCAN_BLOCKS) ? bsum[t] : 0;
    sh[t] = v;
    __syncthreads();
    for (int off = 1; off < 256; off <<= 1) {
        int u = (t >= off) ? sh[t - off] : 0;
        __syncthreads();
        sh[t] += u;
        __syncthreads();
    }
    if (t == blockIdx.x) boff = sh[t] - v;
    __syncthreads();
    int n = blockIdx.x * 256 + t;
    if (n < N_NODES) row_start[n] = local[n] + boff;
}

// ------- CSR fill (no atomics, no dinv): 2-byte entries = src id -------
__global__ void k_fill(const int* __restrict__ src, const int* __restrict__ dst,
                       const int* __restrict__ row_start, const int* __restrict__ rank,
                       unsigned short* __restrict__ entries) {
    int e = blockIdx.x * blockDim.x + threadIdx.x;
    if (e >= N_EDGES) return;
    int pos = row_start[dst[e]] + rank[e];
    entries[pos] = (unsigned short)src[e];
}

// ------- layer-1 gather: 4 threads/node on x' (no coef) + fused BN1 stats --
__global__ __launch_bounds__(256) void k_gather1(const int* __restrict__ row_start,
        const int* __restrict__ cnt, const unsigned short* __restrict__ entries,
        const float* __restrict__ dinv, const float4* __restrict__ xp,
        float4* __restrict__ aggx, const float* __restrict__ W1,
        const float* __restrict__ b1, float* __restrict__ s1, float* __restrict__ q1) {
    __shared__ float axs[64][4];
    __shared__ float w1s[4][128];
    __shared__ float b1s[128];
    __shared__ float red1[256], red2[256];
    int tid = threadIdx.x;
    if (tid < 128) {
        b1s[tid] = b1[tid];
        for (int c2 = 0; c2 < 4; c2++) w1s[c2][tid] = W1[c2 * 128 + tid];
    }
    int t = blockIdx.x * 256 + tid;
    int n = t >> 2, p = t & 3;
    int slot = tid >> 2;
    if (n < N_NODES) {
        int rs = row_start[n], cn = cnt[n];
        const unsigned short* ep = entries + rs;
        float4 accA = make_float4(0.f, 0.f, 0.f, 0.f);
        float4 accB = make_float4(0.f, 0.f, 0.f, 0.f);
        int i = p;
        for (; i + 12 < cn; i += 16) {
            int e0 = ep[i], e1 = ep[i + 4], e2 = ep[i + 8], e3 = ep[i + 12];
            float4 v0 = xp[e0];
            float4 v1 = xp[e1];
            float4 v2 = xp[e2];
            float4 v3 = xp[e3];
            accA.x += v0.x; accA.y += v0.y; accA.z += v0.z; accA.w += v0.w;
            accB.x += v1.x; accB.y += v1.y; accB.z += v1.z; accB.w += v1.w;
            accA.x += v2.x; accA.y += v2.y; accA.z += v2.z; accA.w += v2.w;
            accB.x += v3.x; accB.y += v3.y; accB.z += v3.z; accB.w += v3.w;
        }
        for (; i < cn; i += 4) {
            float4 v = xp[ep[i]];
            accA.x += v.x; accA.y += v.y; accA.z += v.z; accA.w += v.w;
        }
        float ax = accA.x + accB.x, ay = accA.y + accB.y;
        float az = accA.z + accB.z, aw = accA.w + accB.w;
        ax += __shfl_xor(ax, 1); ax += __shfl_xor(ax, 2);
        ay += __shfl_xor(ay, 1); ay += __shfl_xor(ay, 2);
        az += __shfl_xor(az, 1); az += __shfl_xor(az, 2);
        aw += __shfl_xor(aw, 1); aw += __shfl_xor(aw, 2);
        if (p == 0) {
            float di = dinv[n];
            float4 sp = xp[n];
            float4 r = make_float4((ax + sp.x) * di, (ay + sp.y) * di,
                                   (az + sp.z) * di, (aw + sp.w) * di);
            aggx[n] = r;
            axs[slot][0] = r.x; axs[slot][1] = r.y;
            axs[slot][2] = r.z; axs[slot][3] = r.w;
        }
    }
    __syncthreads();
    // phase 2: BN1 stats over this block's 64 nodes, channel-parallel
    int ch = tid & 127, half = tid >> 7;
    int gbase = blockIdx.x * 64;
    float ps = 0.f, pq = 0.f;
    for (int si = 0; si < 32; si++) {
        int sl = half * 32 + si;
        if (gbase + sl < N_NODES) {
            float h = fmaf(axs[sl][0], w1s[0][ch], fmaf(axs[sl][1], w1s[1][ch],
                      fmaf(axs[sl][2], w1s[2][ch], fmaf(axs[sl][3], w1s[3][ch], b1s[ch]))));
            h = fmaxf(h, 0.f);
            ps += h; pq += h * h;
        }
    }
    red1[tid] = ps;
    red2[tid] = pq;
    __syncthreads();
    if (tid < 128) {
        atomicAdd(&s1[tid], red1[tid] + red1[tid + 128]);
        atomicAdd(&q1[tid], red2[tid] + red2[tid + 128]);
    }
}

// ------- fold BN1 into W2 -> W2f (fp16), d2; zero h2' sentinel row ---------
__global__ __launch_bounds__(128) void k_fold1(const float* __restrict__ s1,
        const float* __restrict__ q1, const float* __restrict__ g1,
        const float* __restrict__ be1, const float* __restrict__ W2,
        __half* __restrict__ W2f, float* __restrict__ d2, __half* __restrict__ h2) {
    __shared__ float a[128], c[128];
    int t = threadIdx.x;
    {
        float mean = s1[t] / (float)N_NODES;
        float var  = q1[t] / (float)N_NODES - mean * mean;
        float aa   = rsqrtf(var + BN_EPS) * g1[t];
        a[t] = aa;
        c[t] = be1[t] - mean * aa;
    }
    if (t < 64) h2[(size_t)N_NODES * 64 + t] = __float2half(0.f);   // sentinel row
    __syncthreads();
    if (t < 64) {
        float dd = 0.f;
        for (int k = 0; k < 128; k++) {
            float wv = W2[k * 64 + t];
            W2f[k * 64 + t] = __float2half(a[k] * wv);
            dd = fmaf(c[k], wv, dd);
        }
        d2[t] = dd;
    }
}

// ------- fused: h1 from aggx, GEMM vs fp16 W2f, scale by dinv -> h2' -------
__global__ __launch_bounds__(256) void k_h2(const float4* __restrict__ aggx,
        const float* __restrict__ W1, const float* __restrict__ b1,
        const __half* __restrict__ W2f, const float* __restrict__ d2,
        const float* __restrict__ dinv, __half* __restrict__ h2) {
    __shared__ __half w[128 * 64];
    __shared__ float hs[32][128];
    __shared__ float w1s[4][128];
    __shared__ float b1s[128];
    __shared__ float sdinv[32];
    int tid = threadIdx.x;
    for (int i = tid; i < 1024; i += 256)
        ((uint4*)w)[i] = ((const uint4*)W2f)[i];
    if (tid < 128) {
        b1s[tid] = b1[tid];
        for (int c = 0; c < 4; c++) w1s[c][tid] = W1[c * 128 + tid];
    }
    int n0 = blockIdx.x * 32;
    if (tid < 32) sdinv[tid] = dinv[min(n0 + tid, N_NODES - 1)];
    __syncthreads();
    for (int i = tid; i < 4096; i += 256) {
        int nn = n0 + (i >> 7), j = i & 127;
        float4 a = aggx[min(nn, N_NODES - 1)];
        float h = fmaf(a.x, w1s[0][j], fmaf(a.y, w1s[1][j],
                  fmaf(a.z, w1s[2][j], fmaf(a.w, w1s[3][j], b1s[j]))));
        hs[i >> 7][j] = fmaxf(h, 0.f);
    }
    __syncthreads();
    int j = tid & 63, q = tid >> 6;
    float acc[8];
#pragma unroll
    for (int t = 0; t < 8; t++) acc[t] = 0.f;
    for (int k = 0; k < 128; k++) {
        float wv = __half2float(w[k * 64 + j]);
#pragma unroll
        for (int t = 0; t < 8; t++)
            acc[t] = fmaf(hs[q * 8 + t][k], wv, acc[t]);
    }
    float dj = d2[j];
#pragma unroll
    for (int t = 0; t < 8; t++) {
        int n = n0 + q * 8 + t;
        if (n < N_NODES) h2[n * 64 + j] = __float2half((acc[t] + dj) * sdinv[q * 8 + t]);
    }
}

// ---- helper: 8 halfs (uint4) -> add into acc[8] ----
__device__ __forceinline__ void add8(uint4 v, float* acc) {
    float2 f0 = __half22float2(*reinterpret_cast<const __half2*>(&v.x));
    float2 f1 = __half22float2(*reinterpret_cast<const __half2*>(&v.y));
    float2 f2 = __half22float2(*reinterpret_cast<const __half2*>(&v.z));
    float2 f3 = __half22float2(*reinterpret_cast<const __half2*>(&v.w));
    acc[0] += f0.x; acc[1] += f0.y;
    acc[2] += f1.x; acc[3] += f1.y;
    acc[4] += f2.x; acc[5] += f2.y;
    acc[6] += f3.x; acc[7] += f3.y;
}

// ------- layer-2 gather v15: coef-free sum of h2' rows; grid-stride,
//         2 nodes/wave, 4 edge-slots x 8 ch-lanes, staged 16B loads ---------
__global__ __launch_bounds__(256) void k_gather2(const int* __restrict__ row_start,
        const int* __restrict__ cnt, const unsigned short* __restrict__ entries,
        const float* __restrict__ dinv, const uint4* __restrict__ h2q,
        const float* __restrict__ b2, uint4* __restrict__ out2q,
        float* __restrict__ s2rep, float* __restrict__ q2rep) {
    int lane = threadIdx.x & 63;
    int l32 = lane & 31;
    int es = l32 >> 3;
    int j = l32 & 7;
    int wid = blockIdx.x * 4 + (threadIdx.x >> 6);
    int nwaves = gridDim.x * 4;

    float4 blo = ((const float4*)b2)[2 * j], bhi = ((const float4*)b2)[2 * j + 1];
    float bb[8] = {blo.x, blo.y, blo.z, blo.w, bhi.x, bhi.y, bhi.z, bhi.w};
    float ps[8], pq[8];
#pragma unroll
    for (int t = 0; t < 8; t++) { ps[t] = 0.f; pq[t] = 0.f; }

    for (int base = wid * 2; base < N_NODES; base += nwaves * 2) {
        int n = base + (lane >> 5);
        int rs = row_start[n];
        int cn = cnt[n];
        float di = dinv[n];
        int cm = max(cn, __shfl(cn, lane ^ 32));

        float accA[8], accB[8];
#pragma unroll
        for (int t = 0; t < 8; t++) { accA[t] = 0.f; accB[t] = 0.f; }

        const unsigned short* ep = entries + rs;
        for (int i = 0; i < cm; i += 32) {
            int rem = cn - i;
            int idx = (l32 < rem) ? (int)ep[i + l32] : N_NODES;   // sentinel -> zero row
            int nk = (min(32, cm - i) + 7) >> 3;
            uint4 va[4], vb[4];
#pragma unroll
            for (int k = 0; k < 4; k++) {
                if (k < nk) {
                    int ea = __shfl(idx, 8 * k + es, 32);
                    int eb = __shfl(idx, 8 * k + 4 + es, 32);
                    va[k] = h2q[ea * 8 + j];
                    vb[k] = h2q[eb * 8 + j];
                }
            }
#pragma unroll
            for (int k = 0; k < 4; k++) {
                if (k < nk) {
                    add8(va[k], accA);
                    add8(vb[k], accB);
                }
            }
        }
#pragma unroll
        for (int t = 0; t < 8; t++) {
            float a = accA[t] + accB[t];
            a += __shfl_xor(a, 8);
            a += __shfl_xor(a, 16);
            accA[t] = a;
        }
        if (es == 0) {
            uint4 sv = h2q[n * 8 + j];
            float2 f0 = __half22float2(*reinterpret_cast<const __half2*>(&sv.x));
            float2 f1 = __half22float2(*reinterpret_cast<const __half2*>(&sv.y));
            float2 f2 = __half22float2(*reinterpret_cast<const __half2*>(&sv.z));
            float2 f3 = __half22float2(*reinterpret_cast<const __half2*>(&sv.w));
            float s8[8] = {f0.x, f0.y, f1.x, f1.y, f2.x, f2.y, f3.x, f3.y};
            float r[8];
#pragma unroll
            for (int t = 0; t < 8; t++) {
                r[t] = fmaxf(fmaf(accA[t] + s8[t], di, bb[t]), 0.f);
                ps[t] += r[t];
                pq[t] += r[t] * r[t];
            }
            uint4 o;
            __half2 hp;
            hp = __floats2half2_rn(r[0], r[1]); o.x = *reinterpret_cast<unsigned*>(&hp);
            hp = __floats2half2_rn(r[2], r[3]); o.y = *reinterpret_cast<unsigned*>(&hp);
            hp = __floats2half2_rn(r[4], r[5]); o.z = *reinterpret_cast<unsigned*>(&hp);
            hp = __floats2half2_rn(r[6], r[7]); o.w = *reinterpret_cast<unsigned*>(&hp);
            out2q[n * 8 + j] = o;
        }
    }
    __shared__ float ssum[64], sq[64];
    if (threadIdx.x < 64) { ssum[threadIdx.x] = 0.f; sq[threadIdx.x] = 0.f; }
    __syncthreads();
    if (es == 0) {
#pragma unroll
        for (int t = 0; t < 8; t++) {
            atomicAdd(&ssum[8 * j + t], ps[t]);
            atomicAdd(&sq[8 * j + t], pq[t]);
        }
    }
    __syncthreads();
    if (threadIdx.x < 64) {
        int rep = (blockIdx.x & (NREP - 1)) * 64;
        atomicAdd(&s2rep[rep + threadIdx.x], ssum[threadIdx.x]);
        atomicAdd(&q2rep[rep + threadIdx.x], sq[threadIdx.x]);
    }
}

// ---- 2 waves per graph: BN2-affine pool (linearity-hoisted) + fc1 + stats --
__global__ __launch_bounds__(128) void k_poolfc1(const __half* __restrict__ out2,
        const int* __restrict__ gstart, const float* __restrict__ s2rep,
        const float* __restrict__ q2rep, const float* __restrict__ g2,
        const float* __restrict__ be2, const float* __restrict__ fW1,
        const float* __restrict__ fb1, float* __restrict__ t1,
        float* __restrict__ s3rep, float* __restrict__ q3rep) {
    int g = blockIdx.x;
    int j = threadIdx.x & 63;
    int w = threadIdx.x >> 6;
    int s = gstart[g], e = gstart[g + 1];
    float acc = 0.f;
    int n = s + w;
    for (; n + 6 < e; n += 8) {
        float v0 = __half2float(out2[(n + 0) * 64 + j]);
        float v1 = __half2float(out2[(n + 2) * 64 + j]);
        float v2 = __half2float(out2[(n + 4) * 64 + j]);
        float v3 = __half2float(out2[(n + 6) * 64 + j]);
        acc += (v0 + v1) + (v2 + v3);
    }
    for (; n < e; n += 2) acc += __half2float(out2[n * 64 + j]);
    __shared__ float part[2][64];
    __shared__ float hgs[64];
    part[w][j] = acc;
    __syncthreads();
    if (threadIdx.x < 64) {
        float ssum = 0.f, sq = 0.f;
#pragma unroll
        for (int r = 0; r < NREP; r++) {
            ssum += s2rep[r * 64 + j];
            sq   += q2rep[r * 64 + j];
        }
        float mean = ssum / (float)N_NODES;
        float var  = sq / (float)N_NODES - mean * mean;
        float a = rsqrtf(var + BN_EPS) * g2[j];
        float c = be2[j] - mean * a;
        float asum = part[0][j] + part[1][j];
        hgs[j] = fmaf(a, asum, (float)(e - s) * c);
    }
    __syncthreads();
    if (threadIdx.x < 64) {
        float accf = fb1[j];
        for (int k = 0; k < 64; k++) accf = fmaf(hgs[k], fW1[k * 64 + j], accf);
        accf = fmaxf(accf, 0.f);
        t1[g * 64 + j] = accf;
        int rep = (g & (NREP3 - 1)) * 64;
        atomicAdd(&s3rep[rep + j], accf);
        atomicAdd(&q3rep[rep + j], accf * accf);
    }
}

// ------- bn3 (stats from 16 replicas) -> fc2+relu -> fc3 -> log_softmax ---
__global__ __launch_bounds__(256) void k_final(const float* __restrict__ t1,
        const float* __restrict__ s3rep, const float* __restrict__ q3rep,
        const float* __restrict__ g3, const float* __restrict__ be3,
        const float* __restrict__ fW2, const float* __restrict__ fb2,
        const float* __restrict__ fW3, const float* __restrict__ fb3,
        float* __restrict__ out) {
    __shared__ float w2[64 * 64];
    __shared__ float w3s[192];
    __shared__ float a3[64], c3[64], b3s[3];
    int tid = threadIdx.x;
    for (int i = tid; i < 4096; i += 256) w2[i] = fW2[i];
    if (tid < 192) w3s[tid] = fW3[tid];
    if (tid < 64) {
        float ss = 0.f, qq = 0.f;
#pragma unroll
        for (int r = 0; r < NREP3; r++) {
            ss += s3rep[r * 64 + tid];
            qq += q3rep[r * 64 + tid];
        }
        float mean = ss / (float)NGRAPH;
        float var  = qq / (float)NGRAPH - mean * mean;
        float a = rsqrtf(var + BN_EPS) * g3[tid];
        a3[tid] = a;
        c3[tid] = be3[tid] - mean * a;
    }
    if (tid < 3)  b3s[tid] = fb3[tid];
    __syncthreads();
    int lane = tid & 63, wv = tid >> 6;
    float fbj = fb2[lane];
    for (int r = blockIdx.x * 4 + wv; r < NGRAPH; r += gridDim.x * 4) {
        float acc = fbj;
        for (int k = 0; k < 64; k++) {
            float xk = fmaf(t1[r * 64 + k], a3[k], c3[k]);
            acc = fmaf(xk, w2[k * 64 + lane], acc);
        }
        acc = fmaxf(acc, 0.f);
        float o0 = acc * w3s[lane * 3 + 0];
        float o1 = acc * w3s[lane * 3 + 1];
        float o2 = acc * w3s[lane * 3 + 2];
        for (int off = 32; off; off >>= 1) {
            o0 += __shfl_down(o0, off);
            o1 += __shfl_down(o1, off);
            o2 += __shfl_down(o2, off);
        }
        if (lane == 0) {
            o0 += b3s[0]; o1 += b3s[1]; o2 += b3s[2];
            float m = fmaxf(o0, fmaxf(o1, o2));
            float lse = m + logf(expf(o0 - m) + expf(o1 - m) + expf(o2 - m));
            out[r * 3 + 0] = o0 - lse;
            out[r * 3 + 1] = o1 - lse;
            out[r * 3 + 2] = o2 - lse;
        }
    }
}

extern "C" void kernel_launch(void* const* d_in, const int* in_sizes, int n_in,
                              void* d_out, int out_size, void* d_ws, size_t ws_size,
                              hipStream_t stream) {
    const float* x   = (const float*)d_in[0];
    const int*   ei  = (const int*)d_in[1];
    const int*   bat = (const int*)d_in[2];
    const float* W1  = (const float*)d_in[3];
    const float* b1  = (const float*)d_in[4];
    const float* g1  = (const float*)d_in[5];
    const float* be1 = (const float*)d_in[6];
    const float* W2  = (const float*)d_in[7];
    const float* b2  = (const float*)d_in[8];
    const float* g2  = (const float*)d_in[9];
    const float* be2 = (const float*)d_in[10];
    const float* fW1 = (const float*)d_in[11];
    const float* fb1 = (const float*)d_in[12];
    const float* g3  = (const float*)d_in[13];
    const float* be3 = (const float*)d_in[14];
    const float* fW2 = (const float*)d_in[15];
    const float* fb2 = (const float*)d_in[16];
    const float* fW3 = (const float*)d_in[17];
    const float* fb3 = (const float*)d_in[18];

    // ---- workspace layout ----
    // zeroed region: cnt | s1 q1 | s2rep q2rep | s3rep q3rep
    int*   cnt    = (int*)d_ws;                       // N
    float* s1     = (float*)(cnt + N_NODES);          // 128
    float* q1     = s1 + 128;                         // 128
    float* s2rep  = q1 + 128;                         // NREP*64
    float* q2rep  = s2rep + NREP * 64;                // NREP*64
    float* s3rep  = q2rep + NREP * 64;                // NREP3*64
    float* q3rep  = s3rep + NREP3 * 64;               // NREP3*64
    size_t zero_floats = (size_t)N_NODES + 256 + NREP * 128 + NREP3 * 128;
    // non-zeroed scratch
    float* dinv   = q3rep + NREP3 * 64;               // N
    int*   row_start = (int*)(dinv + N_NODES);        // N
    int*   slocal = row_start + N_NODES;              // N
    int*   sbsum  = slocal + N_NODES;                 // pad 256
    int*   rank   = sbsum + 256;                      // E
    int*   gstart = rank + N_EDGES;                   // 513 (pad 520)
    unsigned short* entries = (unsigned short*)(gstart + 520);  // E ushorts
    float* xp     = (float*)(entries + N_EDGES);      // N*4  (x' = dinv*x)
    float* aggx   = xp + (size_t)N_NODES * 4;         // N*4
    __half* h2    = (__half*)(aggx + (size_t)N_NODES * 4);   // [N+1][64] halfs
    __half* out2  = h2 + (size_t)(N_NODES + 1) * 64;  // [N][64] halfs
    __half* W2f   = out2 + (size_t)N_NODES * 64;      // 128*64 halfs
    float* d2     = (float*)(W2f + 128 * 64);         // 64
    float* t1     = d2 + 64;                          // 512*64

    hipMemsetAsync(d_ws, 0, zero_floats * 4, stream);

    const int* src = ei;
    const int* dst = ei + N_EDGES;

    k_degb   <<<(N_EDGES + 255) / 256, 256, 0, stream>>>(dst, cnt, rank, bat, gstart);
    k_scanA  <<<SCAN_BLOCKS, 256, 0, stream>>>(cnt, dinv, (const float4*)x, (float4*)xp, slocal, sbsum);
    k_scanBC <<<SCAN_BLOCKS, 256, 0, stream>>>(sbsum, slocal, row_start);
    k_fill   <<<(N_EDGES + 255) / 256, 256, 0, stream>>>(src, dst, row_start, rank, entries);
    k_gather1<<<(4 * N_NODES + 255) / 256, 256, 0, stream>>>(row_start, cnt, entries, dinv,
                                                             (const float4*)xp, (float4*)aggx,
                                                             W1, b1, s1, q1);
    k_fold1  <<<1, 128, 0, stream>>>(s1, q1, g1, be1, W2, W2f, d2, h2);
    k_h2     <<<(N_NODES + 31) / 32, 256, 0, stream>>>((const float4*)aggx, W1, b1, W2f, d2, dinv, h2);
    k_gather2<<<4096, 256, 0, stream>>>(row_start, cnt, entries, dinv, (const uint4*)h2, b2, (uint4*)out2, s2rep, q2rep);
    k_poolfc1<<<NGRAPH, 128, 0, stream>>>(out2, gstart, s2rep, q2rep, g2, be2, fW1, fb1, t1, s3rep, q3rep);
    k_final  <<<128, 256, 0, stream>>>(t1, s3rep, q3rep, g3, be3, fW2, fb2, fW3, fb3, (float*)d_out);
}

// Round 16
// 182.699 us; speedup vs baseline: 1.0584x; 1.0163x over previous
//
#include <hip/hip_runtime.h>
#include <hip/hip_fp16.h>
#include <math.h>

#define N_NODES 50000
#define N_EDGES 800000
#define NGRAPH  512
#define BN_EPS  1e-5f
#define SCAN_BLOCKS 196   // ceil(50000/256)
#define NREP 32           // stats replication for k_gather2
#define NREP3 16          // stats replication for k_poolfc1

// ------- degree count + rank; fused graph-boundary scan -------
__global__ void k_degb(const int* __restrict__ dst, int* __restrict__ cnt,
                       int* __restrict__ rank, const int* __restrict__ batch,
                       int* __restrict__ gstart) {
    int e = blockIdx.x * blockDim.x + threadIdx.x;
    if (e < N_EDGES) rank[e] = atomicAdd(&cnt[dst[e]], 1);
    if (e < N_NODES) {
        int b = batch[e];
        int prev = (e == 0) ? -1 : batch[e - 1];
        for (int g = prev + 1; g <= b; g++) gstart[g] = e;
        if (e == N_NODES - 1)
            for (int g = b + 1; g <= NGRAPH; g++) gstart[g] = N_NODES;
    }
}

// ------- scan A: per-256-chunk exclusive scan + dinv + x' = dinv*x ------
__global__ __launch_bounds__(256) void k_scanA(const int* __restrict__ cnt,
        float* __restrict__ dinv, const float4* __restrict__ x, float4* __restrict__ xp,
        int* __restrict__ local, int* __restrict__ bsum) {
    int t = threadIdx.x;
    int n = blockIdx.x * 256 + t;
    int v = 0;
    if (n < N_NODES) {
        v = cnt[n];
        float di = rsqrtf((float)v + 1.0f);
        dinv[n] = di;
        float4 a = x[n];
        xp[n] = make_float4(a.x * di, a.y * di, a.z * di, a.w * di);
    }
    __shared__ int sh[256];
    sh[t] = v;
    __syncthreads();
    for (int off = 1; off < 256; off <<= 1) {
        int u = (t >= off) ? sh[t - off] : 0;
        __syncthreads();
        sh[t] += u;
        __syncthreads();
    }
    if (n < N_NODES) local[n] = sh[t] - v;
    if (t == 255) bsum[blockIdx.x] = sh[255];
}

// ------- fill + inline block-offset scan: every block scans the 196 block
//         sums in LDS; blocks 0..195 also write their row_start chunk -------
__global__ __launch_bounds__(256) void k_fillsc(const int* __restrict__ src,
        const int* __restrict__ dst, const int* __restrict__ local,
        const int* __restrict__ bsum, const int* __restrict__ rank,
        unsigned short* __restrict__ entries, int* __restrict__ row_start) {
    __shared__ int sh[256];
    __shared__ int boffs[256];
    int t = threadIdx.x;
    int v = (t < SCAN_BLOCKS) ? bsum[t] : 0;
    sh[t] = v;
    __syncthreads();
    for (int off = 1; off < 256; off <<= 1) {
        int u = (t >= off) ? sh[t - off] : 0;
        __syncthreads();
        sh[t] += u;
        __syncthreads();
    }
    boffs[t] = sh[t] - v;   // exclusive offsets
    __syncthreads();
    int idx = blockIdx.x * 256 + t;
    if (idx < N_NODES) row_start[idx] = local[idx] + boffs[idx >> 8];
    if (idx < N_EDGES) {
        int d = dst[idx];
        int pos = local[d] + boffs[d >> 8] + rank[idx];
        entries[pos] = (unsigned short)src[idx];
    }
}

// ------- layer-1 gather: 4 threads/node on x' (no coef) + fused BN1 stats --
__global__ __launch_bounds__(256) void k_gather1(const int* __restrict__ row_start,
        const int* __restrict__ cnt, const unsigned short* __restrict__ entries,
        const float* __restrict__ dinv, const float4* __restrict__ xp,
        float4* __restrict__ aggx, const float* __restrict__ W1,
        const float* __restrict__ b1, float* __restrict__ s1, float* __restrict__ q1) {
    __shared__ float axs[64][4];
    __shared__ float w1s[4][128];
    __shared__ float b1s[128];
    __shared__ float red1[256], red2[256];
    int tid = threadIdx.x;
    if (tid < 128) {
        b1s[tid] = b1[tid];
        for (int c2 = 0; c2 < 4; c2++) w1s[c2][tid] = W1[c2 * 128 + tid];
    }
    int t = blockIdx.x * 256 + tid;
    int n = t >> 2, p = t & 3;
    int slot = tid >> 2;
    if (n < N_NODES) {
        int rs = row_start[n], cn = cnt[n];
        const unsigned short* ep = entries + rs;
        float4 accA = make_float4(0.f, 0.f, 0.f, 0.f);
        float4 accB = make_float4(0.f, 0.f, 0.f, 0.f);
        int i = p;
        for (; i + 12 < cn; i += 16) {
            int e0 = ep[i], e1 = ep[i + 4], e2 = ep[i + 8], e3 = ep[i + 12];
            float4 v0 = xp[e0];
            float4 v1 = xp[e1];
            float4 v2 = xp[e2];
            float4 v3 = xp[e3];
            accA.x += v0.x; accA.y += v0.y; accA.z += v0.z; accA.w += v0.w;
            accB.x += v1.x; accB.y += v1.y; accB.z += v1.z; accB.w += v1.w;
            accA.x += v2.x; accA.y += v2.y; accA.z += v2.z; accA.w += v2.w;
            accB.x += v3.x; accB.y += v3.y; accB.z += v3.z; accB.w += v3.w;
        }
        for (; i < cn; i += 4) {
            float4 v = xp[ep[i]];
            accA.x += v.x; accA.y += v.y; accA.z += v.z; accA.w += v.w;
        }
        float ax = accA.x + accB.x, ay = accA.y + accB.y;
        float az = accA.z + accB.z, aw = accA.w + accB.w;
        ax += __shfl_xor(ax, 1); ax += __shfl_xor(ax, 2);
        ay += __shfl_xor(ay, 1); ay += __shfl_xor(ay, 2);
        az += __shfl_xor(az, 1); az += __shfl_xor(az, 2);
        aw += __shfl_xor(aw, 1); aw += __shfl_xor(aw, 2);
        if (p == 0) {
            float di = dinv[n];
            float4 sp = xp[n];
            float4 r = make_float4((ax + sp.x) * di, (ay + sp.y) * di,
                                   (az + sp.z) * di, (aw + sp.w) * di);
            aggx[n] = r;
            axs[slot][0] = r.x; axs[slot][1] = r.y;
            axs[slot][2] = r.z; axs[slot][3] = r.w;
        }
    }
    __syncthreads();
    int ch = tid & 127, half = tid >> 7;
    int gbase = blockIdx.x * 64;
    float ps = 0.f, pq = 0.f;
    for (int si = 0; si < 32; si++) {
        int sl = half * 32 + si;
        if (gbase + sl < N_NODES) {
            float h = fmaf(axs[sl][0], w1s[0][ch], fmaf(axs[sl][1], w1s[1][ch],
                      fmaf(axs[sl][2], w1s[2][ch], fmaf(axs[sl][3], w1s[3][ch], b1s[ch]))));
            h = fmaxf(h, 0.f);
            ps += h; pq += h * h;
        }
    }
    red1[tid] = ps;
    red2[tid] = pq;
    __syncthreads();
    if (tid < 128) {
        atomicAdd(&s1[tid], red1[tid] + red1[tid + 128]);
        atomicAdd(&q1[tid], red2[tid] + red2[tid + 128]);
    }
}

// ------- fold BN1 into W2 -> W2f (fp16), d2; zero h2' sentinel row ---------
__global__ __launch_bounds__(128) void k_fold1(const float* __restrict__ s1,
        const float* __restrict__ q1, const float* __restrict__ g1,
        const float* __restrict__ be1, const float* __restrict__ W2,
        __half* __restrict__ W2f, float* __restrict__ d2, __half* __restrict__ h2) {
    __shared__ float a[128], c[128];
    int t = threadIdx.x;
    {
        float mean = s1[t] / (float)N_NODES;
        float var  = q1[t] / (float)N_NODES - mean * mean;
        float aa   = rsqrtf(var + BN_EPS) * g1[t];
        a[t] = aa;
        c[t] = be1[t] - mean * aa;
    }
    if (t < 64) h2[(size_t)N_NODES * 64 + t] = __float2half(0.f);   // sentinel row
    __syncthreads();
    if (t < 64) {
        float dd = 0.f;
        for (int k = 0; k < 128; k++) {
            float wv = W2[k * 64 + t];
            W2f[k * 64 + t] = __float2half(a[k] * wv);
            dd = fmaf(c[k], wv, dd);
        }
        d2[t] = dd;
    }
}

// ------- fused: h1 from aggx (TRANSPOSED hs for b128 LDS reads),
//         GEMM vs fp16 W2f, scale by dinv -> h2' ----------------------------
__global__ __launch_bounds__(256) void k_h2(const float4* __restrict__ aggx,
        const float* __restrict__ W1, const float* __restrict__ b1,
        const __half* __restrict__ W2f, const float* __restrict__ d2,
        const float* __restrict__ dinv, __half* __restrict__ h2) {
    __shared__ __half w[128 * 64];
    __shared__ float hs[128][36];   // [channel][node], pad 36 (16B-aligned rows)
    __shared__ float w1s[4][128];
    __shared__ float b1s[128];
    __shared__ float sdinv[32];
    int tid = threadIdx.x;
    for (int i = tid; i < 1024; i += 256)
        ((uint4*)w)[i] = ((const uint4*)W2f)[i];
    if (tid < 128) {
        b1s[tid] = b1[tid];
        for (int c = 0; c < 4; c++) w1s[c][tid] = W1[c * 128 + tid];
    }
    int n0 = blockIdx.x * 32;
    if (tid < 32) sdinv[tid] = dinv[min(n0 + tid, N_NODES - 1)];
    __syncthreads();
    for (int i = tid; i < 4096; i += 256) {
        int node = i >> 7, j = i & 127;
        float4 a = aggx[min(n0 + node, N_NODES - 1)];
        float h = fmaf(a.x, w1s[0][j], fmaf(a.y, w1s[1][j],
                  fmaf(a.z, w1s[2][j], fmaf(a.w, w1s[3][j], b1s[j]))));
        hs[j][node] = fmaxf(h, 0.f);
    }
    __syncthreads();
    int j = tid & 63, q = tid >> 6;
    float acc[8];
#pragma unroll
    for (int t = 0; t < 8; t++) acc[t] = 0.f;
    for (int k = 0; k < 128; k++) {
        float wv = __half2float(w[k * 64 + j]);
        float4 h0 = *reinterpret_cast<const float4*>(&hs[k][q * 8]);
        float4 h1 = *reinterpret_cast<const float4*>(&hs[k][q * 8 + 4]);
        acc[0] = fmaf(h0.x, wv, acc[0]);
        acc[1] = fmaf(h0.y, wv, acc[1]);
        acc[2] = fmaf(h0.z, wv, acc[2]);
        acc[3] = fmaf(h0.w, wv, acc[3]);
        acc[4] = fmaf(h1.x, wv, acc[4]);
        acc[5] = fmaf(h1.y, wv, acc[5]);
        acc[6] = fmaf(h1.z, wv, acc[6]);
        acc[7] = fmaf(h1.w, wv, acc[7]);
    }
    float dj = d2[j];
#pragma unroll
    for (int t = 0; t < 8; t++) {
        int n = n0 + q * 8 + t;
        if (n < N_NODES) h2[n * 64 + j] = __float2half((acc[t] + dj) * sdinv[q * 8 + t]);
    }
}

// ---- helper: 8 halfs (uint4) -> add into acc[8] ----
__device__ __forceinline__ void add8(uint4 v, float* acc) {
    float2 f0 = __half22float2(*reinterpret_cast<const __half2*>(&v.x));
    float2 f1 = __half22float2(*reinterpret_cast<const __half2*>(&v.y));
    float2 f2 = __half22float2(*reinterpret_cast<const __half2*>(&v.z));
    float2 f3 = __half22float2(*reinterpret_cast<const __half2*>(&v.w));
    acc[0] += f0.x; acc[1] += f0.y;
    acc[2] += f1.x; acc[3] += f1.y;
    acc[4] += f2.x; acc[5] += f2.y;
    acc[6] += f3.x; acc[7] += f3.y;
}

// ------- layer-2 gather v15 (unchanged): coef-free sum of h2' rows ---------
__global__ __launch_bounds__(256) void k_gather2(const int* __restrict__ row_start,
        const int* __restrict__ cnt, const unsigned short* __restrict__ entries,
        const float* __restrict__ dinv, const uint4* __restrict__ h2q,
        const float* __restrict__ b2, uint4* __restrict__ out2q,
        float* __restrict__ s2rep, float* __restrict__ q2rep) {
    int lane = threadIdx.x & 63;
    int l32 = lane & 31;
    int es = l32 >> 3;
    int j = l32 & 7;
    int wid = blockIdx.x * 4 + (threadIdx.x >> 6);
    int nwaves = gridDim.x * 4;

    float4 blo = ((const float4*)b2)[2 * j], bhi = ((const float4*)b2)[2 * j + 1];
    float bb[8] = {blo.x, blo.y, blo.z, blo.w, bhi.x, bhi.y, bhi.z, bhi.w};
    float ps[8], pq[8];
#pragma unroll
    for (int t = 0; t < 8; t++) { ps[t] = 0.f; pq[t] = 0.f; }

    for (int base = wid * 2; base < N_NODES; base += nwaves * 2) {
        int n = base + (lane >> 5);
        int rs = row_start[n];
        int cn = cnt[n];
        float di = dinv[n];
        int cm = max(cn, __shfl(cn, lane ^ 32));

        float accA[8], accB[8];
#pragma unroll
        for (int t = 0; t < 8; t++) { accA[t] = 0.f; accB[t] = 0.f; }

        const unsigned short* ep = entries + rs;
        for (int i = 0; i < cm; i += 32) {
            int rem = cn - i;
            int idx = (l32 < rem) ? (int)ep[i + l32] : N_NODES;   // sentinel -> zero row
            int nk = (min(32, cm - i) + 7) >> 3;
            uint4 va[4], vb[4];
#pragma unroll
            for (int k = 0; k < 4; k++) {
                if (k < nk) {
                    int ea = __shfl(idx, 8 * k + es, 32);
                    int eb = __shfl(idx, 8 * k + 4 + es, 32);
                    va[k] = h2q[ea * 8 + j];
                    vb[k] = h2q[eb * 8 + j];
                }
            }
#pragma unroll
            for (int k = 0; k < 4; k++) {
                if (k < nk) {
                    add8(va[k], accA);
                    add8(vb[k], accB);
                }
            }
        }
#pragma unroll
        for (int t = 0; t < 8; t++) {
            float a = accA[t] + accB[t];
            a += __shfl_xor(a, 8);
            a += __shfl_xor(a, 16);
            accA[t] = a;
        }
        if (es == 0) {
            uint4 sv = h2q[n * 8 + j];
            float2 f0 = __half22float2(*reinterpret_cast<const __half2*>(&sv.x));
            float2 f1 = __half22float2(*reinterpret_cast<const __half2*>(&sv.y));
            float2 f2 = __half22float2(*reinterpret_cast<const __half2*>(&sv.z));
            float2 f3 = __half22float2(*reinterpret_cast<const __half2*>(&sv.w));
            float s8[8] = {f0.x, f0.y, f1.x, f1.y, f2.x, f2.y, f3.x, f3.y};
            float r[8];
#pragma unroll
            for (int t = 0; t < 8; t++) {
                r[t] = fmaxf(fmaf(accA[t] + s8[t], di, bb[t]), 0.f);
                ps[t] += r[t];
                pq[t] += r[t] * r[t];
            }
            uint4 o;
            __half2 hp;
            hp = __floats2half2_rn(r[0], r[1]); o.x = *reinterpret_cast<unsigned*>(&hp);
            hp = __floats2half2_rn(r[2], r[3]); o.y = *reinterpret_cast<unsigned*>(&hp);
            hp = __floats2half2_rn(r[4], r[5]); o.z = *reinterpret_cast<unsigned*>(&hp);
            hp = __floats2half2_rn(r[6], r[7]); o.w = *reinterpret_cast<unsigned*>(&hp);
            out2q[n * 8 + j] = o;
        }
    }
    __shared__ float ssum[64], sq[64];
    if (threadIdx.x < 64) { ssum[threadIdx.x] = 0.f; sq[threadIdx.x] = 0.f; }
    __syncthreads();
    if (es == 0) {
#pragma unroll
        for (int t = 0; t < 8; t++) {
            atomicAdd(&ssum[8 * j + t], ps[t]);
            atomicAdd(&sq[8 * j + t], pq[t]);
        }
    }
    __syncthreads();
    if (threadIdx.x < 64) {
        int rep = (blockIdx.x & (NREP - 1)) * 64;
        atomicAdd(&s2rep[rep + threadIdx.x], ssum[threadIdx.x]);
        atomicAdd(&q2rep[rep + threadIdx.x], sq[threadIdx.x]);
    }
}

// ---- 2 waves per graph: BN2-affine pool (linearity-hoisted) + fc1 + stats --
__global__ __launch_bounds__(128) void k_poolfc1(const __half* __restrict__ out2,
        const int* __restrict__ gstart, const float* __restrict__ s2rep,
        const float* __restrict__ q2rep, const float* __restrict__ g2,
        const float* __restrict__ be2, const float* __restrict__ fW1,
        const float* __restrict__ fb1, float* __restrict__ t1,
        float* __restrict__ s3rep, float* __restrict__ q3rep) {
    int g = blockIdx.x;
    int j = threadIdx.x & 63;
    int w = threadIdx.x >> 6;
    int s = gstart[g], e = gstart[g + 1];
    float acc = 0.f;
    int n = s + w;
    for (; n + 6 < e; n += 8) {
        float v0 = __half2float(out2[(n + 0) * 64 + j]);
        float v1 = __half2float(out2[(n + 2) * 64 + j]);
        float v2 = __half2float(out2[(n + 4) * 64 + j]);
        float v3 = __half2float(out2[(n + 6) * 64 + j]);
        acc += (v0 + v1) + (v2 + v3);
    }
    for (; n < e; n += 2) acc += __half2float(out2[n * 64 + j]);
    __shared__ float part[2][64];
    __shared__ float hgs[64];
    part[w][j] = acc;
    __syncthreads();
    if (threadIdx.x < 64) {
        float ssum = 0.f, sq = 0.f;
#pragma unroll
        for (int r = 0; r < NREP; r++) {
            ssum += s2rep[r * 64 + j];
            sq   += q2rep[r * 64 + j];
        }
        float mean = ssum / (float)N_NODES;
        float var  = sq / (float)N_NODES - mean * mean;
        float a = rsqrtf(var + BN_EPS) * g2[j];
        float c = be2[j] - mean * a;
        float asum = part[0][j] + part[1][j];
        hgs[j] = fmaf(a, asum, (float)(e - s) * c);
    }
    __syncthreads();
    if (threadIdx.x < 64) {
        float accf = fb1[j];
        for (int k = 0; k < 64; k++) accf = fmaf(hgs[k], fW1[k * 64 + j], accf);
        accf = fmaxf(accf, 0.f);
        t1[g * 64 + j] = accf;
        int rep = (g & (NREP3 - 1)) * 64;
        atomicAdd(&s3rep[rep + j], accf);
        atomicAdd(&q3rep[rep + j], accf * accf);
    }
}

// ------- bn3 (stats from 16 replicas) -> fc2+relu -> fc3 -> log_softmax ---
__global__ __launch_bounds__(256) void k_final(const float* __restrict__ t1,
        const float* __restrict__ s3rep, const float* __restrict__ q3rep,
        const float* __restrict__ g3, const float* __restrict__ be3,
        const float* __restrict__ fW2, const float* __restrict__ fb2,
        const float* __restrict__ fW3, const float* __restrict__ fb3,
        float* __restrict__ out) {
    __shared__ float w2[64 * 64];
    __shared__ float w3s[192];
    __shared__ float a3[64], c3[64], b3s[3];
    int tid = threadIdx.x;
    for (int i = tid; i < 4096; i += 256) w2[i] = fW2[i];
    if (tid < 192) w3s[tid] = fW3[tid];
    if (tid < 64) {
        float ss = 0.f, qq = 0.f;
#pragma unroll
        for (int r = 0; r < NREP3; r++) {
            ss += s3rep[r * 64 + tid];
            qq += q3rep[r * 64 + tid];
        }
        float mean = ss / (float)NGRAPH;
        float var  = qq / (float)NGRAPH - mean * mean;
        float a = rsqrtf(var + BN_EPS) * g3[tid];
        a3[tid] = a;
        c3[tid] = be3[tid] - mean * a;
    }
    if (tid < 3)  b3s[tid] = fb3[tid];
    __syncthreads();
    int lane = tid & 63, wv = tid >> 6;
    float fbj = fb2[lane];
    for (int r = blockIdx.x * 4 + wv; r < NGRAPH; r += gridDim.x * 4) {
        float acc = fbj;
        for (int k = 0; k < 64; k++) {
            float xk = fmaf(t1[r * 64 + k], a3[k], c3[k]);
            acc = fmaf(xk, w2[k * 64 + lane], acc);
        }
        acc = fmaxf(acc, 0.f);
        float o0 = acc * w3s[lane * 3 + 0];
        float o1 = acc * w3s[lane * 3 + 1];
        float o2 = acc * w3s[lane * 3 + 2];
        for (int off = 32; off; off >>= 1) {
            o0 += __shfl_down(o0, off);
            o1 += __shfl_down(o1, off);
            o2 += __shfl_down(o2, off);
        }
        if (lane == 0) {
            o0 += b3s[0]; o1 += b3s[1]; o2 += b3s[2];
            float m = fmaxf(o0, fmaxf(o1, o2));
            float lse = m + logf(expf(o0 - m) + expf(o1 - m) + expf(o2 - m));
            out[r * 3 + 0] = o0 - lse;
            out[r * 3 + 1] = o1 - lse;
            out[r * 3 + 2] = o2 - lse;
        }
    }
}

extern "C" void kernel_launch(void* const* d_in, const int* in_sizes, int n_in,
                              void* d_out, int out_size, void* d_ws, size_t ws_size,
                              hipStream_t stream) {
    const float* x   = (const float*)d_in[0];
    const int*   ei  = (const int*)d_in[1];
    const int*   bat = (const int*)d_in[2];
    const float* W1  = (const float*)d_in[3];
    const float* b1  = (const float*)d_in[4];
    const float* g1  = (const float*)d_in[5];
    const float* be1 = (const float*)d_in[6];
    const float* W2  = (const float*)d_in[7];
    const float* b2  = (const float*)d_in[8];
    const float* g2  = (const float*)d_in[9];
    const float* be2 = (const float*)d_in[10];
    const float* fW1 = (const float*)d_in[11];
    const float* fb1 = (const float*)d_in[12];
    const float* g3  = (const float*)d_in[13];
    const float* be3 = (const float*)d_in[14];
    const float* fW2 = (const float*)d_in[15];
    const float* fb2 = (const float*)d_in[16];
    const float* fW3 = (const float*)d_in[17];
    const float* fb3 = (const float*)d_in[18];

    // ---- workspace layout ----
    int*   cnt    = (int*)d_ws;                       // N
    float* s1     = (float*)(cnt + N_NODES);          // 128
    float* q1     = s1 + 128;                         // 128
    float* s2rep  = q1 + 128;                         // NREP*64
    float* q2rep  = s2rep + NREP * 64;                // NREP*64
    float* s3rep  = q2rep + NREP * 64;                // NREP3*64
    float* q3rep  = s3rep + NREP3 * 64;               // NREP3*64
    size_t zero_floats = (size_t)N_NODES + 256 + NREP * 128 + NREP3 * 128;
    float* dinv   = q3rep + NREP3 * 64;               // N
    int*   row_start = (int*)(dinv + N_NODES);        // N
    int*   slocal = row_start + N_NODES;              // N
    int*   sbsum  = slocal + N_NODES;                 // pad 256
    int*   rank   = sbsum + 256;                      // E
    int*   gstart = rank + N_EDGES;                   // 513 (pad 520)
    unsigned short* entries = (unsigned short*)(gstart + 520);  // E ushorts
    float* xp     = (float*)(entries + N_EDGES);      // N*4
    float* aggx   = xp + (size_t)N_NODES * 4;         // N*4
    __half* h2    = (__half*)(aggx + (size_t)N_NODES * 4);   // [N+1][64] halfs
    __half* out2  = h2 + (size_t)(N_NODES + 1) * 64;  // [N][64] halfs
    __half* W2f   = out2 + (size_t)N_NODES * 64;      // 128*64 halfs
    float* d2     = (float*)(W2f + 128 * 64);         // 64
    float* t1     = d2 + 64;                          // 512*64

    hipMemsetAsync(d_ws, 0, zero_floats * 4, stream);

    const int* src = ei;
    const int* dst = ei + N_EDGES;

    k_degb   <<<(N_EDGES + 255) / 256, 256, 0, stream>>>(dst, cnt, rank, bat, gstart);
    k_scanA  <<<SCAN_BLOCKS, 256, 0, stream>>>(cnt, dinv, (const float4*)x, (float4*)xp, slocal, sbsum);
    k_fillsc <<<(N_EDGES + 255) / 256, 256, 0, stream>>>(src, dst, slocal, sbsum, rank, entries, row_start);
    k_gather1<<<(4 * N_NODES + 255) / 256, 256, 0, stream>>>(row_start, cnt, entries, dinv,
                                                             (const float4*)xp, (float4*)aggx,
                                                             W1, b1, s1, q1);
    k_fold1  <<<1, 128, 0, stream>>>(s1, q1, g1, be1, W2, W2f, d2, h2);
    k_h2     <<<(N_NODES + 31) / 32, 256, 0, stream>>>((const float4*)aggx, W1, b1, W2f, d2, dinv, h2);
    k_gather2<<<4096, 256, 0, stream>>>(row_start, cnt, entries, dinv, (const uint4*)h2, b2, (uint4*)out2, s2rep, q2rep);
    k_poolfc1<<<NGRAPH, 128, 0, stream>>>(out2, gstart, s2rep, q2rep, g2, be2, fW1, fb1, t1, s3rep, q3rep);
    k_final  <<<128, 256, 0, stream>>>(t1, s3rep, q3rep, g3, be3, fW2, fb2, fW3, fb3, (float*)d_out);
}